// Round 8
// baseline (1268.555 us; speedup 1.0000x reference)
//
#include <hip/hip_runtime.h>

#define BS   16
#define NMEM 256
#define NQ   63
#define T    64          // NQ + 1
#define D    512
#define H    512
#define G4   2048        // 4*H

#define K2C  2.885390081777927f   // 2*log2(e)

typedef __attribute__((ext_vector_type(8))) short short8;
typedef __attribute__((ext_vector_type(4))) float float4v;

// ---------------- workspace layout (float offsets) ----------------
enum : size_t {
    OFF_XW  = 0,                            // [T][BS][G4]
    OFF_YS  = OFF_XW  + (size_t)T*BS*G4,    // [T+1][BS][H]  (fp32, b-major, for q-gemm)
    OFF_HB  = OFF_YS  + (size_t)(T+1)*BS*H, // [T+1][2][8192] bf16 hi/lo (ushort)
    OFF_AF  = OFF_HB  + (size_t)(T+1)*BS*H, // [BS*NMEM][H]
    OFF_Q   = OFF_AF  + (size_t)BS*NMEM*H,  // [T*BS][H]
    OFF_BAR = OFF_Q   + (size_t)T*BS*H,     // 2048 ints
};
// counters (ints): hflag[32] @0 (STRIDE 1: two cache lines);
//                  xcnt[16] @512 stride 16; qbcnt[16] @768 stride 16.

__device__ inline unsigned short bf16_rn(float x) {
    union { float f; unsigned u; } a; a.f = x;
    unsigned r = a.u + 0x7FFFu + ((a.u >> 16) & 1u);
    return (unsigned short)(r >> 16);
}
__device__ inline float bf16_to_f(unsigned short s) {
    union { float f; unsigned u; } a; a.u = ((unsigned)s) << 16;
    return a.f;
}

// ---------------- split-bf16 MFMA GEMM unit (256 threads, 64x64 C tile) ------
// MODE 0: C = ks @ wm        (A plain [M,K], B [K,N])                  af
// MODE 1: C = x @ w_ih^T + b (A virtual from lstm_in/init_i, B [N,K])  xW
// MODE 2: C = ysA @ wq       (A plain [M,K], B [K,N])                  qb
template<int MODE>
__device__ inline void gemm_unit(const float* __restrict__ A, const float* __restrict__ B,
                                 float* __restrict__ C,
                                 const float* __restrict__ bias1, const float* __restrict__ bias2,
                                 const float* __restrict__ init_i,
                                 int N, int K, int tm, int tn, int t2)
{
    const int w = t2 >> 6, lane = t2 & 63;
    const int quad = lane >> 4, l15 = lane & 15;
    const int am = tm + w*16 + l15;
    const float* arow;
    if (MODE == 1) {
        const int tt = am >> 4, bb = am & 15;
        arow = (tt == 0) ? init_i : (A + ((size_t)bb*NQ + (tt-1))*D);
    } else {
        arow = A + (size_t)am*K;
    }
    float4v acch[4] = {{0,0,0,0},{0,0,0,0},{0,0,0,0},{0,0,0,0}};
    float4v accl[4] = {{0,0,0,0},{0,0,0,0},{0,0,0,0},{0,0,0,0}};
    for (int k0 = 0; k0 < K; k0 += 32) {
        const float* ap = arow + k0 + quad*8;
        float4 a0 = *(const float4*)ap, a1 = *(const float4*)(ap+4);
        float av[8] = {a0.x,a0.y,a0.z,a0.w,a1.x,a1.y,a1.z,a1.w};
        short8 ah, al;
#pragma unroll
        for (int i = 0; i < 8; ++i) {
            unsigned short hi = bf16_rn(av[i]);
            ah[i] = (short)hi; al[i] = (short)bf16_rn(av[i] - bf16_to_f(hi));
        }
#pragma unroll
        for (int ni = 0; ni < 4; ++ni) {
            const int n = tn + ni*16 + l15;
            float bv[8];
            if (MODE == 1) {
                const float* bp = B + (size_t)n*K + k0 + quad*8;
                float4 b0 = *(const float4*)bp, b1 = *(const float4*)(bp+4);
                bv[0]=b0.x; bv[1]=b0.y; bv[2]=b0.z; bv[3]=b0.w;
                bv[4]=b1.x; bv[5]=b1.y; bv[6]=b1.z; bv[7]=b1.w;
            } else {
                const float* bp = B + (size_t)(k0 + quad*8)*N + n;
#pragma unroll
                for (int i = 0; i < 8; ++i) bv[i] = bp[(size_t)i*N];
            }
            short8 bh, bl;
#pragma unroll
            for (int i = 0; i < 8; ++i) {
                unsigned short hi = bf16_rn(bv[i]);
                bh[i] = (short)hi; bl[i] = (short)bf16_rn(bv[i] - bf16_to_f(hi));
            }
            acch[ni] = __builtin_amdgcn_mfma_f32_16x16x32_bf16(ah, bh, acch[ni], 0, 0, 0);
            accl[ni] = __builtin_amdgcn_mfma_f32_16x16x32_bf16(al, bh, accl[ni], 0, 0, 0);
            accl[ni] = __builtin_amdgcn_mfma_f32_16x16x32_bf16(ah, bl, accl[ni], 0, 0, 0);
        }
    }
#pragma unroll
    for (int ni = 0; ni < 4; ++ni) {
        const int n = tn + ni*16 + l15;
        float bb = (MODE == 1) ? (bias1[n] + bias2[n]) : 0.f;
        float4v r = acch[ni] + accl[ni];
#pragma unroll
        for (int j = 0; j < 4; ++j) {
            int row = tm + w*16 + quad*4 + j;
            __builtin_nontemporal_store(r[j] + bb, C + (size_t)row*N + n);
        }
    }
}

// ---------------- attention unit (256 threads, one (mc,tc,b) tile) -----------
__device__ inline void attn_unit(const float* __restrict__ af, const float* __restrict__ q,
                                 const float* __restrict__ v, float* __restrict__ out,
                                 int mc, int tc, int b, int t2, float* lds)
{
    float* afs = lds;            // [64][68]
    float* qs  = lds + 4352;     // [4][516]
    float* vs  = lds + 6416;     // [512]
    __syncthreads();             // protect LDS reuse across tiles
    for (int i = t2; i < 4*128; i += 256) {
        int t = i >> 7, h4 = (i & 127) << 2;
        float4 x = *(const float4*)(q + ((size_t)((tc*4 + t)*16 + b) << 9) + h4);
        x.x *= K2C; x.y *= K2C; x.z *= K2C; x.w *= K2C;
        *(float4*)&qs[t*516 + h4] = x;
    }
    for (int i = t2; i < 128; i += 256)
        *(float4*)&vs[i << 2] = *(const float4*)(v + (i << 2));
    const int ml = t2 & 63, tg = t2 >> 6;
    float acc = 0.f;
    for (int hc = 0; hc < 8; ++hc) {
        __syncthreads();
        for (int i = t2; i < 64*16; i += 256) {
            int m = i >> 4, h4 = (i & 15) << 2;
            float4 x = *(const float4*)(af + ((size_t)(b*NMEM + mc*64 + m) << 9) + hc*64 + h4);
            x.x *= K2C; x.y *= K2C; x.z *= K2C; x.w *= K2C;
            *(float4*)&afs[m*68 + h4] = x;
        }
        __syncthreads();
#pragma unroll
        for (int h8 = 0; h8 < 8; ++h8) {
            float4 a0 = *(const float4*)&afs[ml*68 + h8*8 + 0];
            float4 a1 = *(const float4*)&afs[ml*68 + h8*8 + 4];
            float4 v0 = *(const float4*)&vs[hc*64 + h8*8 + 0];
            float4 v1 = *(const float4*)&vs[hc*64 + h8*8 + 4];
            float4 q0 = *(const float4*)&qs[tg*516 + hc*64 + h8*8 + 0];
            float4 q1 = *(const float4*)&qs[tg*516 + hc*64 + h8*8 + 4];
            const float* ap0 = (const float*)&a0; const float* ap1 = (const float*)&a1;
            const float* vp0 = (const float*)&v0; const float* vp1 = (const float*)&v1;
            const float* qp0 = (const float*)&q0; const float* qp1 = (const float*)&q1;
            float s = acc;
#pragma unroll
            for (int j = 0; j < 4; ++j) {
                float e = exp2f(ap0[j] + qp0[j]);
                s = fmaf(vp0[j], __builtin_amdgcn_rcpf(e + 1.f), s);
            }
#pragma unroll
            for (int j = 0; j < 4; ++j) {
                float e = exp2f(ap1[j] + qp1[j]);
                s = fmaf(vp1[j], __builtin_amdgcn_rcpf(e + 1.f), s);
            }
            acc = s;
        }
    }
    float Sv = 0.f;
    for (int i = 0; i < 512; i += 4) {
        float4 t4 = *(const float4*)&vs[i];
        Sv += t4.x + t4.y + t4.z + t4.w;
    }
    out[((size_t)b*T + tc*4 + tg)*NMEM + mc*64 + ml] = Sv - 2.f*acc;
}

// ---------------- mega: xW + af GEMMs (producers, exit early) + LSTM ---------
// lstm blocks: blockIdx % 8 == 0 -> under round-robin block->XCD mapping all
// 32 land on XCD 0 (exactly its 32 CUs). Their per-step release wbl2 then
// flushes only XCD-0's L2 (lstm's own ~3 KB of dirt), never the GEMM blocks'
// output. GEMM blocks (XCDs 1-7) run xW then af tiles and EXIT -> the
// recurrence runs in a poller-free environment (r4 lesson). Speed-only
// heuristic: correctness holds for any mapping (agent-scope ops throughout).
__global__ __launch_bounds__(512, 2) void mega(
    const float* __restrict__ lstm_in,   // [BS][NQ][D]
    const float* __restrict__ init_h,    // [H]
    const float* __restrict__ init_c,    // [H]
    const float* __restrict__ init_i,    // [D]
    const float* __restrict__ w_ih,      // [G4][D]
    const float* __restrict__ w_hh,      // [G4][H]
    const float* __restrict__ b_ih,      // [G4]
    const float* __restrict__ b_hh,      // [G4]
    const float* __restrict__ ks,        // [BS*NMEM][D]
    const float* __restrict__ wm,        // [D][H]
    float* __restrict__ xW, float* __restrict__ ys,
    unsigned short* __restrict__ hbuf, float* __restrict__ af,
    int* __restrict__ flags)
{
    __shared__ float smem[3328];
    const int tid = threadIdx.x;
    int* hflag = flags;          // stride 1: 32 ints = 2 cache lines
    int* xcnt  = flags + 512;    // stride 16

    if ((blockIdx.x & 7) != 0) {
        // ---------- GEMM producer blocks (224 blocks, 448 units) ----------
        const int gidx = blockIdx.x - 1 - (blockIdx.x >> 3);   // 0..223
        const int u  = gidx*2 + (tid >> 8);                    // 0..447
        const int t2 = tid & 255;
        // phase 1: xW = x @ w_ih^T + b  (16 mt x 32 nt = 512 tiles)
        for (int tau = u; tau < 512; tau += 448) {
            const int mt = tau >> 5, nt_ = tau & 31;
            gemm_unit<1>(lstm_in, w_ih, xW, b_ih, b_hh, init_i, G4, D, mt*64, nt_*64, t2);
            __syncthreads();     // drains both units' vmcnt -> stores complete
            if (t2 == 0)
                __hip_atomic_fetch_add(&xcnt[mt*16], 1, __ATOMIC_RELEASE, __HIP_MEMORY_SCOPE_AGENT);
        }
        // phase 2: af = ks @ wm  (64 mt x 8 nt = 512 tiles), then exit
        for (int tau = u; tau < 512; tau += 448) {
            gemm_unit<0>(ks, wm, af, nullptr, nullptr, nullptr, H, D, (tau>>3)*64, (tau&7)*64, t2);
        }
        return;
    }

    // ---------- LSTM recurrence (r4 core; jt = blockIdx/8) ----------
    float* part = smem;              // [8][64][4]
    float* cst  = smem + 2048;       // [16][16]
    float* xwb  = smem + 2304;       // [4][16][16]

    const int jt    = blockIdx.x >> 3;
    const int w     = tid >> 6;
    const int g     = w >> 1;
    const int khalf = w & 1;
    const int lane  = tid & 63;
    const int quad  = lane >> 4;
    const int l15   = lane & 15;

    // one-time weight preload -> bf16 hi/lo B-fragments in VGPRs
    short8 bh[8], bl[8];
    {
        const int row = g*512 + jt*16 + l15;
        const float* wr = w_hh + (size_t)row*H + khalf*256 + quad*8;
#pragma unroll
        for (int kt = 0; kt < 8; ++kt) {
            const float* wp = wr + kt*32;
#pragma unroll
            for (int i = 0; i < 8; ++i) {
                float v = wp[i];
                unsigned short hi = bf16_rn(v);
                bh[kt][i] = (short)hi;
                bl[kt][i] = (short)bf16_rn(v - bf16_to_f(hi));
            }
        }
    }

    const int b2 = tid >> 4, j16 = tid & 15;
    if (tid < 256) cst[b2*16 + j16] = init_c[jt*16 + j16];
    if (tid >= 256) {                 // wait for xW m-group 0, stage xW[0] -> LDS
        while (__hip_atomic_load(&xcnt[0], __ATOMIC_RELAXED, __HIP_MEMORY_SCOPE_AGENT) < 32)
            __builtin_amdgcn_s_sleep(1);
        __builtin_amdgcn_fence(__ATOMIC_ACQUIRE, "agent");
        int ti = tid - 256;
        int bb = ti >> 4, s = ti & 15;
        int gg = s & 3, j4 = (s >> 2) << 2;
        float4 v = *(const float4*)(xW + (size_t)bb*G4 + gg*512 + jt*16 + j4);
        float* dst = xwb + gg*256 + bb*16 + j4;
        dst[0]=v.x; dst[1]=v.y; dst[2]=v.z; dst[3]=v.w;
    }
    __syncthreads();

    for (int t = 0; t < T; ++t) {
        // ---- h_t A-fragments ----
        short8 ah[8], al[8];
        if (t == 0) {
#pragma unroll
            for (int kt = 0; kt < 8; ++kt) {
                const int kbase = ((khalf*8 + kt)*4 + quad)*8;
                float4 h0a = *(const float4*)(init_h + kbase);
                float4 h0b = *(const float4*)(init_h + kbase + 4);
                float hv[8] = {h0a.x,h0a.y,h0a.z,h0a.w,h0b.x,h0b.y,h0b.z,h0b.w};
#pragma unroll
                for (int i = 0; i < 8; ++i) {
                    unsigned short hi = bf16_rn(hv[i]);
                    ah[kt][i] = (short)hi;
                    al[kt][i] = (short)bf16_rn(hv[i] - bf16_to_f(hi));
                }
            }
        } else {
            const short8* hhi = (const short8*)(hbuf + (size_t)t*16384);
            const short8* hlo = hhi + 1024;
#pragma unroll
            for (int kt = 0; kt < 8; ++kt) {
                int c = ((khalf*8 + kt)*4 + quad)*16 + l15;
                ah[kt] = hhi[c];
                al[kt] = hlo[c];
            }
        }
        // ---- split-bf16 MFMA ----
        float4v a0 = {0.f,0.f,0.f,0.f}, a1 = {0.f,0.f,0.f,0.f};
#pragma unroll
        for (int kt = 0; kt < 8; ++kt) {
            a0 = __builtin_amdgcn_mfma_f32_16x16x32_bf16(ah[kt], bh[kt], a0, 0, 0, 0);
            a1 = __builtin_amdgcn_mfma_f32_16x16x32_bf16(al[kt], bh[kt], a1, 0, 0, 0);
            a1 = __builtin_amdgcn_mfma_f32_16x16x32_bf16(ah[kt], bl[kt], a1, 0, 0, 0);
        }
        a0 += a1;
        *(float4v*)&part[(w*64 + lane)*4] = a0;
        __syncthreads();

        // ---- finalize: 256 threads = (b2, j16) ----
        if (tid < 256) {
            const int lsrc = ((b2 >> 2)*16 + j16)*4, r = b2 & 3;
            float gi = part[(0*256) + lsrc + r] + part[(1*256) + lsrc + r] + xwb[0*256 + b2*16 + j16];
            float gf = part[(2*256) + lsrc + r] + part[(3*256) + lsrc + r] + xwb[1*256 + b2*16 + j16];
            float gg = part[(4*256) + lsrc + r] + part[(5*256) + lsrc + r] + xwb[2*256 + b2*16 + j16];
            float go = part[(6*256) + lsrc + r] + part[(7*256) + lsrc + r] + xwb[3*256 + b2*16 + j16];
            float si = 1.f/(1.f+__expf(-gi));
            float sf = 1.f/(1.f+__expf(-gf));
            float so = 1.f/(1.f+__expf(-go));
            float cn = sf*cst[b2*16 + j16] + si*tanhf(gg);
            float hn = so*tanhf(cn);
            cst[b2*16 + j16] = cn;
            __builtin_nontemporal_store(hn, ys + (size_t)(t+1)*BS*H + b2*H + jt*16 + j16);
            const int k = jt*16 + j16;
            const int e = ((k >> 3)*16 + b2)*8 + (k & 7);
            unsigned short hi = bf16_rn(hn);
            unsigned short* hb1 = hbuf + (size_t)(t+1)*16384;
            hb1[e]        = hi;
            hb1[8192 + e] = bf16_rn(hn - bf16_to_f(hi));
        }
        __syncthreads();   // vmcnt drain: all stores complete before flag

        if (t < T-1) {
            if (tid == 0)
                __hip_atomic_store(&hflag[jt], t+1, __ATOMIC_RELEASE, __HIP_MEMORY_SCOPE_AGENT);
            if (tid >= 256) {        // stage xW[t+1] under the flag wait
                const int grp = ((t+1) >> 2) * 16;
                while (__hip_atomic_load(&xcnt[grp], __ATOMIC_RELAXED, __HIP_MEMORY_SCOPE_AGENT) < 32)
                    __builtin_amdgcn_s_sleep(1);
                __builtin_amdgcn_fence(__ATOMIC_ACQUIRE, "agent");
                int ti = tid - 256;
                int bb = ti >> 4, s = ti & 15;
                int gg2 = s & 3, j4 = (s >> 2) << 2;
                float4 v = *(const float4*)(xW + (size_t)(t+1)*BS*G4 + bb*G4 + gg2*512 + jt*16 + j4);
                float* dst = xwb + gg2*256 + bb*16 + j4;
                dst[0]=v.x; dst[1]=v.y; dst[2]=v.z; dst[3]=v.w;
            }
            if (tid < 64) {          // poll: 32 flags in 2 cache lines
                const int fidx = tid & 31;
                for (;;) {
                    int v = __hip_atomic_load(&hflag[fidx], __ATOMIC_RELAXED, __HIP_MEMORY_SCOPE_AGENT);
                    if (__all(v >= t+1)) break;
                    __builtin_amdgcn_s_sleep(1);
                }
                __builtin_amdgcn_fence(__ATOMIC_ACQUIRE, "agent");
            }
            __syncthreads();
        }
    }
}

// ---------------- qb GEMM + attention, one kernel -----------------------------
// blocks 0-127: one qb tile each, release qbcnt[mt]. All 256 blocks: 4 attn
// tiles each, gated on qbcnt[tc] (single-lane poll; post-recurrence, harmless).
__global__ __launch_bounds__(256) void qbattn(
    const float* __restrict__ ys,        // [T+1][BS][H]
    const float* __restrict__ wq,        // [H][H]
    const float* __restrict__ af,        // [BS*NMEM][H]
    const float* __restrict__ av,        // [H]
    float* __restrict__ qb, float* __restrict__ out,
    int* __restrict__ flags)
{
    __shared__ float lds[6928];
    const int tid = threadIdx.x;
    const int b   = blockIdx.x;
    int* qbcnt = flags + 768;

    if (b < 128) {
        const int mt = b >> 3, nt_ = b & 7;
        gemm_unit<2>(ys + BS*H, wq, qb, nullptr, nullptr, nullptr, H, H, mt*64, nt_*64, tid);
        __syncthreads();
        if (tid == 0)
            __hip_atomic_fetch_add(&qbcnt[mt*16], 1, __ATOMIC_RELEASE, __HIP_MEMORY_SCOPE_AGENT);
    }
#pragma unroll
    for (int i = 0; i < 4; ++i) {
        const int tau = b + i*256;                 // 0..1023
        const int tc = tau >> 6, mc = (tau >> 4) & 3, bb = tau & 15;
        if (tid == 0) {
            while (__hip_atomic_load(&qbcnt[tc*16], __ATOMIC_RELAXED, __HIP_MEMORY_SCOPE_AGENT) < 8)
                __builtin_amdgcn_s_sleep(16);
            __builtin_amdgcn_fence(__ATOMIC_ACQUIRE, "agent");
        }
        __syncthreads();
        attn_unit(af, qb, av, out, mc, tc, bb, tid, lds);
    }
}

extern "C" void kernel_launch(void* const* d_in, const int* in_sizes, int n_in,
                              void* d_out, int out_size, void* d_ws, size_t ws_size,
                              hipStream_t stream)
{
    const float* ks      = (const float*)d_in[0];
    const float* lstm_in = (const float*)d_in[2];
    const float* init_h  = (const float*)d_in[3];
    const float* init_c  = (const float*)d_in[4];
    const float* init_i  = (const float*)d_in[5];
    const float* w_ih    = (const float*)d_in[6];
    const float* w_hh    = (const float*)d_in[7];
    const float* b_ih    = (const float*)d_in[8];
    const float* b_hh    = (const float*)d_in[9];
    const float* wm      = (const float*)d_in[10];
    const float* wq      = (const float*)d_in[11];
    const float* av      = (const float*)d_in[12];

    float* ws   = (float*)d_ws;
    float* xW   = ws + OFF_XW;
    float* ys   = ws + OFF_YS;
    unsigned short* hbuf = (unsigned short*)(ws + OFF_HB);
    float* af   = ws + OFF_AF;
    float* qb   = ws + OFF_Q;
    int*   flags= (int*)(ws + OFF_BAR);

    hipMemsetAsync(flags, 0, 2048*sizeof(int), stream);
    // xW + af producers (exit early) + LSTM recurrence, XCD-0-isolated
    mega<<<256, 512, 0, stream>>>(lstm_in, init_h, init_c, init_i,
                                  w_ih, w_hh, b_ih, b_hh, ks, wm,
                                  xW, ys, hbuf, af, flags);
    // qb GEMM + attention
    qbattn<<<256, 256, 0, stream>>>(ys, wq, af, av, qb, (float*)d_out, flags);
}

// Round 9
// 515.854 us; speedup vs baseline: 2.4591x; 2.4591x over previous
//
#include <hip/hip_runtime.h>

#define BS   16
#define NMEM 256
#define NQ   63
#define T    64          // NQ + 1
#define D    512
#define H    512
#define G4   2048        // 4*H

#define K2C  2.885390081777927f   // 2*log2(e)

typedef __attribute__((ext_vector_type(8))) short short8;
typedef __attribute__((ext_vector_type(4))) float float4v;

// ---------------- workspace layout (float offsets) ----------------
enum : size_t {
    OFF_XW  = 0,                            // [T][BS][G4]
    OFF_YS  = OFF_XW  + (size_t)T*BS*G4,    // [T+1][BS][H]  (fp32, b-major, for q-gemm)
    OFF_HB  = OFF_YS  + (size_t)(T+1)*BS*H, // [T+1][2][8192] bf16 hi/lo (ushort)
    OFF_AF  = OFF_HB  + (size_t)(T+1)*BS*H, // [BS*NMEM][H]
    OFF_Q   = OFF_AF  + (size_t)BS*NMEM*H,  // [T*BS][H]
    OFF_BAR = OFF_Q   + (size_t)T*BS*H,     // 2048 ints
};
// counters (ints, ALL stride 16 = one cache line per writer):
//   hflag[32] @0, xcnt[16] @512, qbcnt[16] @768

__device__ inline unsigned short bf16_rn(float x) {
    union { float f; unsigned u; } a; a.f = x;
    unsigned r = a.u + 0x7FFFu + ((a.u >> 16) & 1u);
    return (unsigned short)(r >> 16);
}
__device__ inline float bf16_to_f(unsigned short s) {
    union { float f; unsigned u; } a; a.u = ((unsigned)s) << 16;
    return a.f;
}

// ---------------- split-bf16 MFMA GEMM unit (256 threads, 64x64 C tile) ------
// MODE 0: C = ks @ wm        (A plain [M,K], B [K,N])                  af
// MODE 1: C = x @ w_ih^T + b (A virtual from lstm_in/init_i, B [N,K])  xW
// MODE 2: C = ysA @ wq       (A plain [M,K], B [K,N])                  qb
template<int MODE>
__device__ inline void gemm_unit(const float* __restrict__ A, const float* __restrict__ B,
                                 float* __restrict__ C,
                                 const float* __restrict__ bias1, const float* __restrict__ bias2,
                                 const float* __restrict__ init_i,
                                 int N, int K, int tm, int tn, int t2)
{
    const int w = t2 >> 6, lane = t2 & 63;
    const int quad = lane >> 4, l15 = lane & 15;
    const int am = tm + w*16 + l15;
    const float* arow;
    if (MODE == 1) {
        const int tt = am >> 4, bb = am & 15;
        arow = (tt == 0) ? init_i : (A + ((size_t)bb*NQ + (tt-1))*D);
    } else {
        arow = A + (size_t)am*K;
    }
    float4v acch[4] = {{0,0,0,0},{0,0,0,0},{0,0,0,0},{0,0,0,0}};
    float4v accl[4] = {{0,0,0,0},{0,0,0,0},{0,0,0,0},{0,0,0,0}};
    for (int k0 = 0; k0 < K; k0 += 32) {
        const float* ap = arow + k0 + quad*8;
        float4 a0 = *(const float4*)ap, a1 = *(const float4*)(ap+4);
        float av[8] = {a0.x,a0.y,a0.z,a0.w,a1.x,a1.y,a1.z,a1.w};
        short8 ah, al;
#pragma unroll
        for (int i = 0; i < 8; ++i) {
            unsigned short hi = bf16_rn(av[i]);
            ah[i] = (short)hi; al[i] = (short)bf16_rn(av[i] - bf16_to_f(hi));
        }
#pragma unroll
        for (int ni = 0; ni < 4; ++ni) {
            const int n = tn + ni*16 + l15;
            float bv[8];
            if (MODE == 1) {
                const float* bp = B + (size_t)n*K + k0 + quad*8;
                float4 b0 = *(const float4*)bp, b1 = *(const float4*)(bp+4);
                bv[0]=b0.x; bv[1]=b0.y; bv[2]=b0.z; bv[3]=b0.w;
                bv[4]=b1.x; bv[5]=b1.y; bv[6]=b1.z; bv[7]=b1.w;
            } else {
                const float* bp = B + (size_t)(k0 + quad*8)*N + n;
#pragma unroll
                for (int i = 0; i < 8; ++i) bv[i] = bp[(size_t)i*N];
            }
            short8 bh, bl;
#pragma unroll
            for (int i = 0; i < 8; ++i) {
                unsigned short hi = bf16_rn(bv[i]);
                bh[i] = (short)hi; bl[i] = (short)bf16_rn(bv[i] - bf16_to_f(hi));
            }
            acch[ni] = __builtin_amdgcn_mfma_f32_16x16x32_bf16(ah, bh, acch[ni], 0, 0, 0);
            accl[ni] = __builtin_amdgcn_mfma_f32_16x16x32_bf16(al, bh, accl[ni], 0, 0, 0);
            accl[ni] = __builtin_amdgcn_mfma_f32_16x16x32_bf16(ah, bl, accl[ni], 0, 0, 0);
        }
    }
#pragma unroll
    for (int ni = 0; ni < 4; ++ni) {
        const int n = tn + ni*16 + l15;
        float bb = (MODE == 1) ? (bias1[n] + bias2[n]) : 0.f;
        float4v r = acch[ni] + accl[ni];
#pragma unroll
        for (int j = 0; j < 4; ++j) {
            int row = tm + w*16 + quad*4 + j;
            __builtin_nontemporal_store(r[j] + bb, C + (size_t)row*N + n);
        }
    }
}

// ---------------- attention unit (256 threads, one (mc,tc,b) tile) -----------
__device__ inline void attn_unit(const float* __restrict__ af, const float* __restrict__ q,
                                 const float* __restrict__ v, float* __restrict__ out,
                                 int mc, int tc, int b, int t2, float* lds)
{
    float* afs = lds;            // [64][68]
    float* qs  = lds + 4352;     // [4][516]
    float* vs  = lds + 6416;     // [512]
    __syncthreads();             // protect LDS reuse across tiles
    for (int i = t2; i < 4*128; i += 256) {
        int t = i >> 7, h4 = (i & 127) << 2;
        float4 x = *(const float4*)(q + ((size_t)((tc*4 + t)*16 + b) << 9) + h4);
        x.x *= K2C; x.y *= K2C; x.z *= K2C; x.w *= K2C;
        *(float4*)&qs[t*516 + h4] = x;
    }
    for (int i = t2; i < 128; i += 256)
        *(float4*)&vs[i << 2] = *(const float4*)(v + (i << 2));
    const int ml = t2 & 63, tg = t2 >> 6;
    float acc = 0.f;
    for (int hc = 0; hc < 8; ++hc) {
        __syncthreads();
        for (int i = t2; i < 64*16; i += 256) {
            int m = i >> 4, h4 = (i & 15) << 2;
            float4 x = *(const float4*)(af + ((size_t)(b*NMEM + mc*64 + m) << 9) + hc*64 + h4);
            x.x *= K2C; x.y *= K2C; x.z *= K2C; x.w *= K2C;
            *(float4*)&afs[m*68 + h4] = x;
        }
        __syncthreads();
#pragma unroll
        for (int h8 = 0; h8 < 8; ++h8) {
            float4 a0 = *(const float4*)&afs[ml*68 + h8*8 + 0];
            float4 a1 = *(const float4*)&afs[ml*68 + h8*8 + 4];
            float4 v0 = *(const float4*)&vs[hc*64 + h8*8 + 0];
            float4 v1 = *(const float4*)&vs[hc*64 + h8*8 + 4];
            float4 q0 = *(const float4*)&qs[tg*516 + hc*64 + h8*8 + 0];
            float4 q1 = *(const float4*)&qs[tg*516 + hc*64 + h8*8 + 4];
            const float* ap0 = (const float*)&a0; const float* ap1 = (const float*)&a1;
            const float* vp0 = (const float*)&v0; const float* vp1 = (const float*)&v1;
            const float* qp0 = (const float*)&q0; const float* qp1 = (const float*)&q1;
            float s = acc;
#pragma unroll
            for (int j = 0; j < 4; ++j) {
                float e = exp2f(ap0[j] + qp0[j]);
                s = fmaf(vp0[j], __builtin_amdgcn_rcpf(e + 1.f), s);
            }
#pragma unroll
            for (int j = 0; j < 4; ++j) {
                float e = exp2f(ap1[j] + qp1[j]);
                s = fmaf(vp1[j], __builtin_amdgcn_rcpf(e + 1.f), s);
            }
            acc = s;
        }
    }
    float Sv = 0.f;
    for (int i = 0; i < 512; i += 4) {
        float4 t4 = *(const float4*)&vs[i];
        Sv += t4.x + t4.y + t4.z + t4.w;
    }
    out[((size_t)b*T + tc*4 + tg)*NMEM + mc*64 + ml] = Sv - 2.f*acc;
}

// ---------------- mega: xW + af producers (exit early) + LSTM ----------------
// lstm = blocks 0-31 (r4-exact core and sync fabric: one cache line per flag
// writer, wave-parallel poll). Producer blocks 32-255 run xW tiles (release
// per-m-tile counters), then af tiles, then EXIT -> poller-free recurrence.
__global__ __launch_bounds__(512, 2) void mega(
    const float* __restrict__ lstm_in,   // [BS][NQ][D]
    const float* __restrict__ init_h,    // [H]
    const float* __restrict__ init_c,    // [H]
    const float* __restrict__ init_i,    // [D]
    const float* __restrict__ w_ih,      // [G4][D]
    const float* __restrict__ w_hh,      // [G4][H]
    const float* __restrict__ b_ih,      // [G4]
    const float* __restrict__ b_hh,      // [G4]
    const float* __restrict__ ks,        // [BS*NMEM][D]
    const float* __restrict__ wm,        // [D][H]
    float* __restrict__ xW, float* __restrict__ ys,
    unsigned short* __restrict__ hbuf, float* __restrict__ af,
    int* __restrict__ flags)
{
    __shared__ float smem[3328];
    const int tid = threadIdx.x;
    int* hflag = flags;          // stride 16
    int* xcnt  = flags + 512;    // stride 16

    if (blockIdx.x >= 32) {
        // ---------- GEMM producer blocks (224 blocks, 448 units) ----------
        const int u  = (blockIdx.x - 32)*2 + (tid >> 8);       // 0..447
        const int t2 = tid & 255;
        // phase 1: xW = x @ w_ih^T + b  (16 mt x 32 nt = 512 tiles)
        for (int tau = u; tau < 512; tau += 448) {
            const int mt = tau >> 5, nt_ = tau & 31;
            gemm_unit<1>(lstm_in, w_ih, xW, b_ih, b_hh, init_i, G4, D, mt*64, nt_*64, t2);
            __syncthreads();     // drains both units' vmcnt -> stores complete
            if (t2 == 0)
                __hip_atomic_fetch_add(&xcnt[mt*16], 1, __ATOMIC_RELEASE, __HIP_MEMORY_SCOPE_AGENT);
        }
        // phase 2: af = ks @ wm  (64 mt x 8 nt = 512 tiles), then exit
        for (int tau = u; tau < 512; tau += 448) {
            gemm_unit<0>(ks, wm, af, nullptr, nullptr, nullptr, H, D, (tau>>3)*64, (tau&7)*64, t2);
        }
        return;
    }

    // ---------- LSTM recurrence (r4-exact core) ----------
    float* part = smem;              // [8][64][4]
    float* cst  = smem + 2048;       // [16][16]
    float* xwb  = smem + 2304;       // [4][16][16]

    const int jt    = blockIdx.x;
    const int w     = tid >> 6;
    const int g     = w >> 1;
    const int khalf = w & 1;
    const int lane  = tid & 63;
    const int quad  = lane >> 4;
    const int l15   = lane & 15;

    // one-time weight preload -> bf16 hi/lo B-fragments in VGPRs
    short8 bh[8], bl[8];
    {
        const int row = g*512 + jt*16 + l15;
        const float* wr = w_hh + (size_t)row*H + khalf*256 + quad*8;
#pragma unroll
        for (int kt = 0; kt < 8; ++kt) {
            const float* wp = wr + kt*32;
#pragma unroll
            for (int i = 0; i < 8; ++i) {
                float v = wp[i];
                unsigned short hi = bf16_rn(v);
                bh[kt][i] = (short)hi;
                bl[kt][i] = (short)bf16_rn(v - bf16_to_f(hi));
            }
        }
    }

    const int b2 = tid >> 4, j16 = tid & 15;
    if (tid < 256) cst[b2*16 + j16] = init_c[jt*16 + j16];
    if (tid >= 256) {                 // wait for xW m-group 0, stage xW[0] -> LDS
        while (__hip_atomic_load(&xcnt[0], __ATOMIC_RELAXED, __HIP_MEMORY_SCOPE_AGENT) < 32)
            __builtin_amdgcn_s_sleep(1);
        __builtin_amdgcn_fence(__ATOMIC_ACQUIRE, "agent");
        int ti = tid - 256;
        int bb = ti >> 4, s = ti & 15;
        int gg = s & 3, j4 = (s >> 2) << 2;
        float4 v = *(const float4*)(xW + (size_t)bb*G4 + gg*512 + jt*16 + j4);
        float* dst = xwb + gg*256 + bb*16 + j4;
        dst[0]=v.x; dst[1]=v.y; dst[2]=v.z; dst[3]=v.w;
    }
    __syncthreads();

    for (int t = 0; t < T; ++t) {
        // ---- h_t A-fragments ----
        short8 ah[8], al[8];
        if (t == 0) {
#pragma unroll
            for (int kt = 0; kt < 8; ++kt) {
                const int kbase = ((khalf*8 + kt)*4 + quad)*8;
                float4 h0a = *(const float4*)(init_h + kbase);
                float4 h0b = *(const float4*)(init_h + kbase + 4);
                float hv[8] = {h0a.x,h0a.y,h0a.z,h0a.w,h0b.x,h0b.y,h0b.z,h0b.w};
#pragma unroll
                for (int i = 0; i < 8; ++i) {
                    unsigned short hi = bf16_rn(hv[i]);
                    ah[kt][i] = (short)hi;
                    al[kt][i] = (short)bf16_rn(hv[i] - bf16_to_f(hi));
                }
            }
        } else {
            const short8* hhi = (const short8*)(hbuf + (size_t)t*16384);
            const short8* hlo = hhi + 1024;
#pragma unroll
            for (int kt = 0; kt < 8; ++kt) {
                int c = ((khalf*8 + kt)*4 + quad)*16 + l15;
                ah[kt] = hhi[c];
                al[kt] = hlo[c];
            }
        }
        // ---- split-bf16 MFMA ----
        float4v a0 = {0.f,0.f,0.f,0.f}, a1 = {0.f,0.f,0.f,0.f};
#pragma unroll
        for (int kt = 0; kt < 8; ++kt) {
            a0 = __builtin_amdgcn_mfma_f32_16x16x32_bf16(ah[kt], bh[kt], a0, 0, 0, 0);
            a1 = __builtin_amdgcn_mfma_f32_16x16x32_bf16(al[kt], bh[kt], a1, 0, 0, 0);
            a1 = __builtin_amdgcn_mfma_f32_16x16x32_bf16(ah[kt], bl[kt], a1, 0, 0, 0);
        }
        a0 += a1;
        *(float4v*)&part[(w*64 + lane)*4] = a0;
        __syncthreads();

        // ---- finalize: 256 threads = (b2, j16) ----
        if (tid < 256) {
            const int lsrc = ((b2 >> 2)*16 + j16)*4, r = b2 & 3;
            float gi = part[(0*256) + lsrc + r] + part[(1*256) + lsrc + r] + xwb[0*256 + b2*16 + j16];
            float gf = part[(2*256) + lsrc + r] + part[(3*256) + lsrc + r] + xwb[1*256 + b2*16 + j16];
            float gg = part[(4*256) + lsrc + r] + part[(5*256) + lsrc + r] + xwb[2*256 + b2*16 + j16];
            float go = part[(6*256) + lsrc + r] + part[(7*256) + lsrc + r] + xwb[3*256 + b2*16 + j16];
            float si = 1.f/(1.f+__expf(-gi));
            float sf = 1.f/(1.f+__expf(-gf));
            float so = 1.f/(1.f+__expf(-go));
            float cn = sf*cst[b2*16 + j16] + si*tanhf(gg);
            float hn = so*tanhf(cn);
            cst[b2*16 + j16] = cn;
            __builtin_nontemporal_store(hn, ys + (size_t)(t+1)*BS*H + b2*H + jt*16 + j16);
            const int k = jt*16 + j16;
            const int e = ((k >> 3)*16 + b2)*8 + (k & 7);
            unsigned short hi = bf16_rn(hn);
            unsigned short* hb1 = hbuf + (size_t)(t+1)*16384;
            hb1[e]        = hi;
            hb1[8192 + e] = bf16_rn(hn - bf16_to_f(hi));
        }
        __syncthreads();   // vmcnt drain: all stores complete before flag

        if (t < T-1) {
            if (tid == 0)
                __hip_atomic_store(&hflag[jt*16], t+1, __ATOMIC_RELEASE, __HIP_MEMORY_SCOPE_AGENT);
            if (tid >= 256) {        // stage xW[t+1] under the flag wait
                const int grp = ((t+1) >> 2) * 16;
                while (__hip_atomic_load(&xcnt[grp], __ATOMIC_RELAXED, __HIP_MEMORY_SCOPE_AGENT) < 32)
                    __builtin_amdgcn_s_sleep(1);
                __builtin_amdgcn_fence(__ATOMIC_ACQUIRE, "agent");
                int ti = tid - 256;
                int bb = ti >> 4, s = ti & 15;
                int gg2 = s & 3, j4 = (s >> 2) << 2;
                float4 v = *(const float4*)(xW + (size_t)(t+1)*BS*G4 + bb*G4 + gg2*512 + jt*16 + j4);
                float* dst = xwb + gg2*256 + bb*16 + j4;
                dst[0]=v.x; dst[1]=v.y; dst[2]=v.z; dst[3]=v.w;
            }
            if (tid < 64) {          // wave-parallel poll of 32 flags (r4-exact)
                const int fidx = (tid & 31) << 4;
                for (;;) {
                    int v = __hip_atomic_load(&hflag[fidx], __ATOMIC_RELAXED, __HIP_MEMORY_SCOPE_AGENT);
                    if (__all(v >= t+1)) break;
                    __builtin_amdgcn_s_sleep(1);
                }
                __builtin_amdgcn_fence(__ATOMIC_ACQUIRE, "agent");
            }
            __syncthreads();
        }
    }
}

// ---------------- qb GEMM + attention, one kernel -----------------------------
// blocks 0-127: one qb tile each, release qbcnt[mt]. All 256 blocks: 4 attn
// tiles each, gated on qbcnt[tc] (single-lane poll; post-recurrence, harmless).
__global__ __launch_bounds__(256) void qbattn(
    const float* __restrict__ ys,        // [T+1][BS][H]
    const float* __restrict__ wq,        // [H][H]
    const float* __restrict__ af,        // [BS*NMEM][H]
    const float* __restrict__ av,        // [H]
    float* __restrict__ qb, float* __restrict__ out,
    int* __restrict__ flags)
{
    __shared__ float lds[6928];
    const int tid = threadIdx.x;
    const int b   = blockIdx.x;
    int* qbcnt = flags + 768;

    if (b < 128) {
        const int mt = b >> 3, nt_ = b & 7;
        gemm_unit<2>(ys + BS*H, wq, qb, nullptr, nullptr, nullptr, H, H, mt*64, nt_*64, tid);
        __syncthreads();
        if (tid == 0)
            __hip_atomic_fetch_add(&qbcnt[mt*16], 1, __ATOMIC_RELEASE, __HIP_MEMORY_SCOPE_AGENT);
    }
#pragma unroll
    for (int i = 0; i < 4; ++i) {
        const int tau = b + i*256;                 // 0..1023
        const int tc = tau >> 6, mc = (tau >> 4) & 3, bb = tau & 15;
        if (tid == 0) {
            while (__hip_atomic_load(&qbcnt[tc*16], __ATOMIC_RELAXED, __HIP_MEMORY_SCOPE_AGENT) < 8)
                __builtin_amdgcn_s_sleep(16);
            __builtin_amdgcn_fence(__ATOMIC_ACQUIRE, "agent");
        }
        __syncthreads();
        attn_unit(af, qb, av, out, mc, tc, bb, tid, lds);
    }
}

extern "C" void kernel_launch(void* const* d_in, const int* in_sizes, int n_in,
                              void* d_out, int out_size, void* d_ws, size_t ws_size,
                              hipStream_t stream)
{
    const float* ks      = (const float*)d_in[0];
    const float* lstm_in = (const float*)d_in[2];
    const float* init_h  = (const float*)d_in[3];
    const float* init_c  = (const float*)d_in[4];
    const float* init_i  = (const float*)d_in[5];
    const float* w_ih    = (const float*)d_in[6];
    const float* w_hh    = (const float*)d_in[7];
    const float* b_ih    = (const float*)d_in[8];
    const float* b_hh    = (const float*)d_in[9];
    const float* wm      = (const float*)d_in[10];
    const float* wq      = (const float*)d_in[11];
    const float* av      = (const float*)d_in[12];

    float* ws   = (float*)d_ws;
    float* xW   = ws + OFF_XW;
    float* ys   = ws + OFF_YS;
    unsigned short* hbuf = (unsigned short*)(ws + OFF_HB);
    float* af   = ws + OFF_AF;
    float* qb   = ws + OFF_Q;
    int*   flags= (int*)(ws + OFF_BAR);

    hipMemsetAsync(flags, 0, 2048*sizeof(int), stream);
    // xW + af producers (exit early) + LSTM recurrence
    mega<<<256, 512, 0, stream>>>(lstm_in, init_h, init_c, init_i,
                                  w_ih, w_hh, b_ih, b_hh, ks, wm,
                                  xW, ys, hbuf, af, flags);
    // qb GEMM + attention
    qbattn<<<256, 256, 0, stream>>>(ys, wq, af, av, qb, (float*)d_out, flags);
}